// Round 1
// baseline (2429.915 us; speedup 1.0000x reference)
//
#include <hip/hip_runtime.h>
#include <math.h>

#define NPTS 16384
#define NBATCH 8
#define CIN 128
#define COUT 256
#define NP 1024
#define NS 32

// ---------------- FPS ----------------
// One block per batch. Points + running dist live entirely in registers.
// Exact f32 replication of reference: d = ((dx*dx + dy*dy) + dz*dz), dist=min,
// argmax with first-index tie-break.
#define FT 512
#define FP (NPTS / FT)  // 32 points per thread, contiguous chunk

__global__ __launch_bounds__(FT, 1)
void fps_kernel(const float* __restrict__ xyz, int* __restrict__ fps_idx)
{
#pragma clang fp contract(off)
  const int b = blockIdx.x;
  const float* __restrict__ X = xyz + (size_t)b * NPTS * 3;
  const int tid = threadIdx.x;
  const int base = tid * FP;

  float px[FP], py[FP], pz[FP], dist[FP];
#pragma unroll
  for (int i = 0; i < FP; ++i) {
    px[i] = X[(base + i) * 3 + 0];
    py[i] = X[(base + i) * 3 + 1];
    pz[i] = X[(base + i) * 3 + 2];
    dist[i] = 1e10f;
  }

  __shared__ float redv[FT / 64];
  __shared__ int   redi[FT / 64];
  __shared__ float redc[FT / 64][3];

  int cur = 0;
  float lx = X[0], ly = X[1], lz = X[2];

  for (int k = 0; k < NP; ++k) {
    if (tid == 0) fps_idx[b * NP + k] = cur;

    float bmax = -1.0f;
    int bidx = 0;
#pragma unroll
    for (int i = 0; i < FP; ++i) {
      float dx = px[i] - lx;
      float dy = py[i] - ly;
      float dz = pz[i] - lz;
      float d = ((dx * dx) + (dy * dy)) + (dz * dz);  // contract(off): exact op order
      float nd = fminf(dist[i], d);
      dist[i] = nd;
      bool g = nd > bmax;               // strict >: first occurrence wins ties
      bmax = g ? nd : bmax;
      bidx = g ? (base + i) : bidx;
    }
    // wave-level argmax reduce (64 lanes), tie-break smaller index
#pragma unroll
    for (int off = 32; off >= 1; off >>= 1) {
      float ov = __shfl_xor(bmax, off);
      int   oi = __shfl_xor(bidx, off);
      bool t = (ov > bmax) || (ov == bmax && oi < bidx);
      bmax = t ? ov : bmax;
      bidx = t ? oi : bidx;
    }
    const int w = tid >> 6;
    if ((tid & 63) == 0) {
      redv[w] = bmax;
      redi[w] = bidx;
      // speculative coord fetch of this wave's candidate: overlaps the barrier,
      // removes dependent global load from the post-reduce critical path
      const float* pc = X + (size_t)bidx * 3;
      redc[w][0] = pc[0]; redc[w][1] = pc[1]; redc[w][2] = pc[2];
    }
    __syncthreads();
    float bv = redv[0]; int bi = redi[0]; int bw = 0;
#pragma unroll
    for (int j = 1; j < FT / 64; ++j) {
      float v = redv[j]; int ii = redi[j];
      bool t = (v > bv) || (v == bv && ii < bi);
      bv = t ? v : bv; bi = t ? ii : bi; bw = t ? j : bw;
    }
    cur = bi;
    lx = redc[bw][0]; ly = redc[bw][1]; lz = redc[bw][2];
    __syncthreads();  // protect red* from next iteration's writes
  }
}

// ---------------- Ball query ----------------
// One wave per center; ordered scan with early exit once 32 found.
// Exact replication of expanded-form distance: (n2 + x2) - 2*dot.
__global__ __launch_bounds__(256)
void ballq_kernel(const float* __restrict__ xyz, const int* __restrict__ fps_idx,
                  int* __restrict__ ball_idx)
{
#pragma clang fp contract(off)
  const int gw = (int)((blockIdx.x * blockDim.x + threadIdx.x) >> 6);
  const int lane = threadIdx.x & 63;
  const int b = gw >> 10, s = gw & 1023;
  const float* __restrict__ X = xyz + (size_t)b * NPTS * 3;
  const int ci = fps_idx[b * NP + s];
  const float cx = X[ci * 3 + 0], cy = X[ci * 3 + 1], cz = X[ci * 3 + 2];
  const float n2 = ((cx * cx) + (cy * cy)) + (cz * cz);
  int* __restrict__ out = ball_idx + (size_t)(b * NP + s) * NS;

  int cnt = 0;
  int first = -1;
  for (int c0 = 0; c0 < NPTS && cnt < NS; c0 += 64) {
    const int p = c0 + lane;
    const float x = X[p * 3 + 0], y = X[p * 3 + 1], z = X[p * 3 + 2];
    const float x2 = ((x * x) + (y * y)) + (z * z);
    const float dt = ((cx * x) + (cy * y)) + (cz * z);
    const float d2 = (n2 + x2) - (2.0f * dt);
    const bool inball = d2 < 0.04f;  // fl32(0.04), matches weak-scalar promotion
    const unsigned long long m = __ballot(inball);
    if (inball) {
      const int pos = cnt + __popcll(m & ((1ull << lane) - 1ull));
      if (pos < NS) out[pos] = p;
    }
    if (first < 0 && m != 0ull) first = c0 + __builtin_ctzll(m);
    cnt += __popcll(m);
  }
  if (cnt < NS) {
    if (first < 0) first = 0;  // count==0 => reference fills with index 0
    if (lane >= cnt && lane < NS) out[lane] = first;
  }
}

// ---------------- Transpose feats [B][C][N] -> [B][N][C] ----------------
__global__ __launch_bounds__(256)
void transpose_kernel(const float* __restrict__ feats, float* __restrict__ featsT)
{
  __shared__ float t[32][33];
  const int b = blockIdx.z;
  const int cb = blockIdx.y * 32;
  const int nb = blockIdx.x * 32;
  const int tx = threadIdx.x;  // 32
  const int ty = threadIdx.y;  // 8
  const float* __restrict__ F = feats + (size_t)b * CIN * NPTS;
#pragma unroll
  for (int i = 0; i < 32; i += 8)
    t[ty + i][tx] = F[(size_t)(cb + ty + i) * NPTS + nb + tx];
  __syncthreads();
  float* __restrict__ FT_ = featsT + (size_t)b * NPTS * CIN;
#pragma unroll
  for (int i = 0; i < 32; i += 8)
    FT_[(size_t)(nb + ty + i) * CIN + cb + tx] = t[tx][ty + i];
}

// ---------------- Gather + max-pool ----------------
__global__ __launch_bounds__(128)
void pool_kernel(const float* __restrict__ featsT, const int* __restrict__ ball_idx,
                 float* __restrict__ pooled)
{
  const int bs = blockIdx.x;  // b*1024 + s
  const int c = threadIdx.x;
  const int b = bs >> 10;
  const int* __restrict__ idx = ball_idx + (size_t)bs * NS;
  const float* __restrict__ FT_ = featsT + (size_t)b * NPTS * CIN;
  float m = -INFINITY;
#pragma unroll 4
  for (int k = 0; k < NS; ++k) {
    const int n = idx[k];
    m = fmaxf(m, FT_[(size_t)n * CIN + c]);
  }
  pooled[(size_t)bs * CIN + c] = m;  // layout [b][s][c]
}

// ---------------- 1x1 conv + BN + LeakyReLU ----------------
#define GO 128  // output-channel tile
#define GS 64   // s tile
__global__ __launch_bounds__(256, 1)
void gemm_kernel(const float* __restrict__ pooled, const float* __restrict__ W,
                 const float* __restrict__ gamma, const float* __restrict__ beta,
                 const float* __restrict__ mean, const float* __restrict__ var,
                 float* __restrict__ out)
{
  __shared__ float Wt[128 * 132];  // [c][o], stride 132 (16B-aligned rows, padded)
  __shared__ float Pl[128 * 68];   // [c][s], stride 68
  const int b = blockIdx.z;
  const int ob = blockIdx.y * GO;
  const int sb = blockIdx.x * GS;
  const int tid = threadIdx.x;

  for (int i = tid; i < GO * 128; i += 256) {
    const int o = i >> 7, c = i & 127;
    Wt[c * 132 + o] = W[(ob + o) * 128 + c];
  }
  const float* __restrict__ P = pooled + (size_t)(b * NP + sb) * 128;
  for (int i = tid; i < GS * 128; i += 256) {
    const int s = i >> 7, c = i & 127;
    Pl[c * 68 + s] = P[s * 128 + c];
  }
  __syncthreads();

  const int to = tid & 31, ts = tid >> 5;
  const int o0 = to * 4, s0 = ts * 8;
  float acc[4][8];
#pragma unroll
  for (int o = 0; o < 4; ++o)
#pragma unroll
    for (int j = 0; j < 8; ++j) acc[o][j] = 0.0f;

  for (int c = 0; c < 128; ++c) {
    const float4 wv = *(const float4*)&Wt[c * 132 + o0];
    const float4 pa = *(const float4*)&Pl[c * 68 + s0];
    const float4 pb = *(const float4*)&Pl[c * 68 + s0 + 4];
    const float wr[4] = {wv.x, wv.y, wv.z, wv.w};
    const float pr[8] = {pa.x, pa.y, pa.z, pa.w, pb.x, pb.y, pb.z, pb.w};
#pragma unroll
    for (int o = 0; o < 4; ++o)
#pragma unroll
      for (int j = 0; j < 8; ++j)
        acc[o][j] = fmaf(wr[o], pr[j], acc[o][j]);
  }

#pragma unroll
  for (int o = 0; o < 4; ++o) {
    const int oo = ob + o0 + o;
    const float sc = gamma[oo] / sqrtf(var[oo] + 1e-5f);
    const float sh = beta[oo] - mean[oo] * sc;
    float r[8];
#pragma unroll
    for (int j = 0; j < 8; ++j) {
      const float y = fmaf(acc[o][j], sc, sh);
      r[j] = (y >= 0.0f) ? y : 0.2f * y;
    }
    float* __restrict__ O = out + (size_t)(b * COUT + oo) * NP + sb + s0;
    *(float4*)&O[0] = make_float4(r[0], r[1], r[2], r[3]);
    *(float4*)&O[4] = make_float4(r[4], r[5], r[6], r[7]);
  }
}

// ---------------- launch ----------------
extern "C" void kernel_launch(void* const* d_in, const int* in_sizes, int n_in,
                              void* d_out, int out_size, void* d_ws, size_t ws_size,
                              hipStream_t stream)
{
  (void)in_sizes; (void)n_in; (void)out_size; (void)ws_size;
  const float* xyz   = (const float*)d_in[0];
  const float* feats = (const float*)d_in[1];
  const float* W     = (const float*)d_in[2];
  const float* gamma = (const float*)d_in[3];
  const float* beta  = (const float*)d_in[4];
  const float* mean  = (const float*)d_in[5];
  const float* var   = (const float*)d_in[6];
  float* out = (float*)d_out;

  char* ws = (char*)d_ws;
  // layout: fps_idx [8*1024 i32] @0 (32 KB) | ball_idx [8*1024*32 i32] @32768 (1 MB)
  //         featsT [8*16384*128 f32] @1081344 (64 MB) | pooled [8*1024*128 f32] @68190208 (4 MB)
  int*   fps_idx  = (int*)(ws + 0);
  int*   ball_idx = (int*)(ws + 32768);
  float* featsT   = (float*)(ws + 1081344);
  float* pooled   = (float*)(ws + 68190208);

  fps_kernel<<<NBATCH, FT, 0, stream>>>(xyz, fps_idx);
  ballq_kernel<<<(NBATCH * NP) / 4, 256, 0, stream>>>(xyz, fps_idx, ball_idx);
  transpose_kernel<<<dim3(NPTS / 32, CIN / 32, NBATCH), dim3(32, 8), 0, stream>>>(feats, featsT);
  pool_kernel<<<NBATCH * NP, CIN, 0, stream>>>(featsT, ball_idx, pooled);
  gemm_kernel<<<dim3(NP / GS, COUT / GO, NBATCH), 256, 0, stream>>>(pooled, W, gamma, beta, mean, var, out);
}

// Round 2
// 1916.227 us; speedup vs baseline: 1.2681x; 1.2681x over previous
//
#include <hip/hip_runtime.h>
#include <math.h>

#define NPTS 16384
#define NBATCH 8
#define CIN 128
#define COUT 256
#define NP 1024
#define NS 32

// ---------------- FPS (multi-CU, lock-free slot sync) ----------------
// 16 blocks x 64 threads per batch (grid 128). Each block owns 1024 contiguous
// points (16/thread, in registers). Per iteration: local update+argmax ->
// wave butterfly -> publish {k|idx|val} u64 slot (agent-scope atomic, parity
// double-buffered) -> spin-read all 16 slots -> combine -> broadcast-load
// winner coords from xyz. Exact f32 replication of reference (contract off,
// ((dx*dx+dy*dy)+dz*dz), min, argmax first-occurrence).
#define FPS_M 16      // blocks per batch
#define FPS_PT 16     // points per thread

__global__ void fps_init_kernel(unsigned long long* __restrict__ slots)
{
  // sentinel tag k=2047 (never a real iteration) in all 8*2*16 = 256 slots
  slots[threadIdx.x] = (unsigned long long)2047ull << 46;
}

__global__ __launch_bounds__(64, 1)
void fps_kernel(const float* __restrict__ xyz, int* __restrict__ fps_idx,
                unsigned long long* __restrict__ slots)
{
#pragma clang fp contract(off)
  const int b = blockIdx.x & 7;        // batch (blockIdx%8 -> same XCD if round-robin)
  const int m = blockIdx.x >> 3;       // member 0..15
  const int lane = threadIdx.x;        // 64
  const float* __restrict__ X = xyz + (size_t)b * NPTS * 3;
  const int base = m * (NPTS / FPS_M) + lane * FPS_PT;
  unsigned long long* __restrict__ bs = slots + b * (2 * FPS_M);

  float px[FPS_PT], py[FPS_PT], pz[FPS_PT], dist[FPS_PT];
#pragma unroll
  for (int i = 0; i < FPS_PT; ++i) {
    px[i] = X[(base + i) * 3 + 0];
    py[i] = X[(base + i) * 3 + 1];
    pz[i] = X[(base + i) * 3 + 2];
    dist[i] = 1e10f;
  }

  int cur = 0;
  float lx = X[0], ly = X[1], lz = X[2];

  for (int k = 0; k < NP; ++k) {
    if (m == 0 && lane == 0) fps_idx[b * NP + k] = cur;

    // local update + argmax (first-occurrence via strict >, ascending i)
    float bmax = -1.0f;
    int bidx = 0;
#pragma unroll
    for (int i = 0; i < FPS_PT; ++i) {
      float dx = px[i] - lx;
      float dy = py[i] - ly;
      float dz = pz[i] - lz;
      float d = ((dx * dx) + (dy * dy)) + (dz * dz);  // exact ref op order
      float nd = fminf(dist[i], d);
      dist[i] = nd;
      bool g = nd > bmax;
      bmax = g ? nd : bmax;
      bidx = g ? (base + i) : bidx;
    }
    // 64-lane argmax butterfly, tie -> min idx (lanes are index-ordered)
#pragma unroll
    for (int off = 32; off >= 1; off >>= 1) {
      float ov = __shfl_xor(bmax, off);
      int   oi = __shfl_xor(bidx, off);
      bool t = (ov > bmax) || (ov == bmax && oi < bidx);
      bmax = t ? ov : bmax;
      bidx = t ? oi : bidx;
    }
    // publish this block's partial
    if (lane == 0) {
      unsigned long long pk = ((unsigned long long)(unsigned)k << 46)
                            | ((unsigned long long)(unsigned)bidx << 32)
                            | (unsigned long long)__float_as_uint(bmax);
      __hip_atomic_store(&bs[(k & 1) * FPS_M + m], pk,
                         __ATOMIC_RELAXED, __HIP_MEMORY_SCOPE_AGENT);
    }
    // spin: lane j < 16 polls slot j until tag == k
    unsigned long long v = 0;
    bool ok = (lane >= FPS_M);
    const unsigned long long* sl = &bs[(k & 1) * FPS_M + (lane & (FPS_M - 1))];
    while (true) {
      if (!ok) {
        v = __hip_atomic_load(sl, __ATOMIC_RELAXED, __HIP_MEMORY_SCOPE_AGENT);
        ok = (int)((v >> 46) & 2047ull) == k;
      }
      if (__all(ok)) break;
    }
    // combine 16 partials (lanes 0..15), tie -> min idx
    float rv = (lane < FPS_M) ? __uint_as_float((unsigned)(v & 0xFFFFFFFFull)) : -1.0f;
    int   ri = (lane < FPS_M) ? (int)((v >> 32) & 16383ull) : (1 << 30);
#pragma unroll
    for (int off = 8; off >= 1; off >>= 1) {
      float ov = __shfl_xor(rv, off);
      int   oi = __shfl_xor(ri, off);
      bool t = (ov > rv) || (ov == rv && oi < ri);
      rv = t ? ov : rv;
      ri = t ? oi : ri;
    }
    cur = __shfl(ri, 0);
    lx = X[cur * 3 + 0];  // uniform broadcast load
    ly = X[cur * 3 + 1];
    lz = X[cur * 3 + 2];
  }
}

// ---------------- Ball query ----------------
__global__ __launch_bounds__(256)
void ballq_kernel(const float* __restrict__ xyz, const int* __restrict__ fps_idx,
                  int* __restrict__ ball_idx)
{
#pragma clang fp contract(off)
  const int gw = (int)((blockIdx.x * blockDim.x + threadIdx.x) >> 6);
  const int lane = threadIdx.x & 63;
  const int b = gw >> 10, s = gw & 1023;
  const float* __restrict__ X = xyz + (size_t)b * NPTS * 3;
  const int ci = fps_idx[b * NP + s];
  const float cx = X[ci * 3 + 0], cy = X[ci * 3 + 1], cz = X[ci * 3 + 2];
  const float n2 = ((cx * cx) + (cy * cy)) + (cz * cz);
  int* __restrict__ out = ball_idx + (size_t)(b * NP + s) * NS;

  int cnt = 0;
  int first = -1;
  for (int c0 = 0; c0 < NPTS && cnt < NS; c0 += 64) {
    const int p = c0 + lane;
    const float x = X[p * 3 + 0], y = X[p * 3 + 1], z = X[p * 3 + 2];
    const float x2 = ((x * x) + (y * y)) + (z * z);
    const float dt = ((cx * x) + (cy * y)) + (cz * z);
    const float d2 = (n2 + x2) - (2.0f * dt);
    const bool inball = d2 < 0.04f;
    const unsigned long long mm = __ballot(inball);
    if (inball) {
      const int pos = cnt + __popcll(mm & ((1ull << lane) - 1ull));
      if (pos < NS) out[pos] = p;
    }
    if (first < 0 && mm != 0ull) first = c0 + __builtin_ctzll(mm);
    cnt += __popcll(mm);
  }
  if (cnt < NS) {
    if (first < 0) first = 0;
    if (lane >= cnt && lane < NS) out[lane] = first;
  }
}

// ---------------- Transpose feats [B][C][N] -> [B][N][C] ----------------
__global__ __launch_bounds__(256)
void transpose_kernel(const float* __restrict__ feats, float* __restrict__ featsT)
{
  __shared__ float t[32][33];
  const int b = blockIdx.z;
  const int cb = blockIdx.y * 32;
  const int nb = blockIdx.x * 32;
  const int tx = threadIdx.x;  // 32
  const int ty = threadIdx.y;  // 8
  const float* __restrict__ F = feats + (size_t)b * CIN * NPTS;
#pragma unroll
  for (int i = 0; i < 32; i += 8)
    t[ty + i][tx] = F[(size_t)(cb + ty + i) * NPTS + nb + tx];
  __syncthreads();
  float* __restrict__ FT_ = featsT + (size_t)b * NPTS * CIN;
#pragma unroll
  for (int i = 0; i < 32; i += 8)
    FT_[(size_t)(nb + ty + i) * CIN + cb + tx] = t[tx][ty + i];
}

// ---------------- Gather + max-pool ----------------
__global__ __launch_bounds__(128)
void pool_kernel(const float* __restrict__ featsT, const int* __restrict__ ball_idx,
                 float* __restrict__ pooled)
{
  const int bs = blockIdx.x;  // b*1024 + s
  const int c = threadIdx.x;
  const int b = bs >> 10;
  const int* __restrict__ idx = ball_idx + (size_t)bs * NS;
  const float* __restrict__ FT_ = featsT + (size_t)b * NPTS * CIN;
  float m = -INFINITY;
#pragma unroll 4
  for (int k = 0; k < NS; ++k) {
    const int n = idx[k];
    m = fmaxf(m, FT_[(size_t)n * CIN + c]);
  }
  pooled[(size_t)bs * CIN + c] = m;  // layout [b][s][c]
}

// ---------------- 1x1 conv + BN + LeakyReLU ----------------
#define GO 128
#define GS 64
__global__ __launch_bounds__(256, 1)
void gemm_kernel(const float* __restrict__ pooled, const float* __restrict__ W,
                 const float* __restrict__ gamma, const float* __restrict__ beta,
                 const float* __restrict__ mean, const float* __restrict__ var,
                 float* __restrict__ out)
{
  __shared__ float Wt[128 * 132];
  __shared__ float Pl[128 * 68];
  const int b = blockIdx.z;
  const int ob = blockIdx.y * GO;
  const int sb = blockIdx.x * GS;
  const int tid = threadIdx.x;

  for (int i = tid; i < GO * 128; i += 256) {
    const int o = i >> 7, c = i & 127;
    Wt[c * 132 + o] = W[(ob + o) * 128 + c];
  }
  const float* __restrict__ P = pooled + (size_t)(b * NP + sb) * 128;
  for (int i = tid; i < GS * 128; i += 256) {
    const int s = i >> 7, c = i & 127;
    Pl[c * 68 + s] = P[s * 128 + c];
  }
  __syncthreads();

  const int to = tid & 31, ts = tid >> 5;
  const int o0 = to * 4, s0 = ts * 8;
  float acc[4][8];
#pragma unroll
  for (int o = 0; o < 4; ++o)
#pragma unroll
    for (int j = 0; j < 8; ++j) acc[o][j] = 0.0f;

  for (int c = 0; c < 128; ++c) {
    const float4 wv = *(const float4*)&Wt[c * 132 + o0];
    const float4 pa = *(const float4*)&Pl[c * 68 + s0];
    const float4 pb = *(const float4*)&Pl[c * 68 + s0 + 4];
    const float wr[4] = {wv.x, wv.y, wv.z, wv.w};
    const float pr[8] = {pa.x, pa.y, pa.z, pa.w, pb.x, pb.y, pb.z, pb.w};
#pragma unroll
    for (int o = 0; o < 4; ++o)
#pragma unroll
      for (int j = 0; j < 8; ++j)
        acc[o][j] = fmaf(wr[o], pr[j], acc[o][j]);
  }

#pragma unroll
  for (int o = 0; o < 4; ++o) {
    const int oo = ob + o0 + o;
    const float sc = gamma[oo] / sqrtf(var[oo] + 1e-5f);
    const float sh = beta[oo] - mean[oo] * sc;
    float r[8];
#pragma unroll
    for (int j = 0; j < 8; ++j) {
      const float y = fmaf(acc[o][j], sc, sh);
      r[j] = (y >= 0.0f) ? y : 0.2f * y;
    }
    float* __restrict__ O = out + (size_t)(b * COUT + oo) * NP + sb + s0;
    *(float4*)&O[0] = make_float4(r[0], r[1], r[2], r[3]);
    *(float4*)&O[4] = make_float4(r[4], r[5], r[6], r[7]);
  }
}

// ---------------- launch ----------------
extern "C" void kernel_launch(void* const* d_in, const int* in_sizes, int n_in,
                              void* d_out, int out_size, void* d_ws, size_t ws_size,
                              hipStream_t stream)
{
  (void)in_sizes; (void)n_in; (void)out_size; (void)ws_size;
  const float* xyz   = (const float*)d_in[0];
  const float* feats = (const float*)d_in[1];
  const float* W     = (const float*)d_in[2];
  const float* gamma = (const float*)d_in[3];
  const float* beta  = (const float*)d_in[4];
  const float* mean  = (const float*)d_in[5];
  const float* var   = (const float*)d_in[6];
  float* out = (float*)d_out;

  char* ws = (char*)d_ws;
  // layout: fps_idx [32KB] @0 | ball_idx [1MB] @32768 | featsT [64MB] @1081344
  //         pooled [4MB] @68190208
  // fps slots (2KB) overlap featsT's head: slots dead before transpose runs.
  int*   fps_idx  = (int*)(ws + 0);
  int*   ball_idx = (int*)(ws + 32768);
  float* featsT   = (float*)(ws + 1081344);
  float* pooled   = (float*)(ws + 68190208);
  unsigned long long* slots = (unsigned long long*)(ws + 1081344);

  fps_init_kernel<<<1, NBATCH * 2 * FPS_M, 0, stream>>>(slots);
  fps_kernel<<<NBATCH * FPS_M, 64, 0, stream>>>(xyz, fps_idx, slots);
  ballq_kernel<<<(NBATCH * NP) / 4, 256, 0, stream>>>(xyz, fps_idx, ball_idx);
  transpose_kernel<<<dim3(NPTS / 32, CIN / 32, NBATCH), dim3(32, 8), 0, stream>>>(feats, featsT);
  pool_kernel<<<NBATCH * NP, CIN, 0, stream>>>(featsT, ball_idx, pooled);
  gemm_kernel<<<dim3(NP / GS, COUT / GO, NBATCH), 256, 0, stream>>>(pooled, W, gamma, beta, mean, var, out);
}